// Round 7
// baseline (456.183 us; speedup 1.0000x reference)
//
#include <hip/hip_runtime.h>

typedef float v2f __attribute__((ext_vector_type(2)));

// Problem constants (from reference)
constexpr int I_N = 3, H_N = 2048, O_N = 2, S_N = 4, G_N = 7;
constexpr int B_N = 32, T_N = 512;
constexpr int TPB = 512;          // threads per block (8 waves)
constexpr int EPT = H_N / TPB;    // 4 consecutive h-elements per thread
constexpr float ALPHA_C = 0.2f;
constexpr float NSTD_C = 0.05f;
constexpr float TWO_LOG2E = 2.885390081777927f;  // 2*log2(e)

// tanh(x) = 1 - 2/(exp2(2*log2e*x)+1); inf-safe both ends
__device__ __forceinline__ float fast_tanh(float x) {
  float e = __builtin_amdgcn_exp2f(x * TWO_LOG2E);
  return fmaf(-2.0f, __builtin_amdgcn_rcpf(e + 1.0f), 1.0f);
}

#define DPP_ADD(x, ctrl, rmask)                                                \
  x += __int_as_float(__builtin_amdgcn_update_dpp(                             \
      0, __float_as_int(x), (ctrl), (rmask), 0xf, true))

// Full 64-lane sum -> lane 63 (row_shr moves data to HIGHER lanes)
__device__ __forceinline__ float wave_sum63(float x) {
  DPP_ADD(x, 0x111, 0xf);  // row_shr:1
  DPP_ADD(x, 0x112, 0xf);  // row_shr:2
  DPP_ADD(x, 0x114, 0xf);  // row_shr:4
  DPP_ADD(x, 0x118, 0xf);  // row_shr:8
  DPP_ADD(x, 0x142, 0xa);  // row_bcast15 -> lane31
  DPP_ADD(x, 0x143, 0xc);  // row_bcast31 -> lane63
  return x;
}

__device__ __forceinline__ float rfl(float v) {
  return __int_as_float(__builtin_amdgcn_readfirstlane(__float_as_int(v)));
}

// ---------------- kernel0: precompute wo_full (H,2) into ws ----------------
__global__ __launch_bounds__(256) void wo_precomp(
    const float* __restrict__ wo, const float* __restrict__ gb,
    const float* __restrict__ sup, float2* __restrict__ ws2) {
  const int h = blockIdx.x * 256 + threadIdx.x;
  const int s = h >> 9;
  const float sv = sup[s * H_N + h];
  float c0 = 0.f, c1 = 0.f;
#pragma unroll
  for (int g = 0; g < G_N; ++g) {
    const float gv = gb[g * H_N + h];
    c0 = fmaf(wo[(0 * S_N + s) * G_N + g], gv, c0);
    c1 = fmaf(wo[(1 * S_N + s) * G_N + g], gv, c1);
  }
  ws2[h] = make_float2(c0 * sv, c1 * sv);
}

// ------------- kernel2: out[b,t] = tanh(traj[b,t,:]) @ wo_full -------------
__global__ __launch_bounds__(256) void out_proj(
    const float* __restrict__ traj, const float2* __restrict__ ws2,
    float* __restrict__ out) {
  const int blk = blockIdx.x;          // b*T + t
  const int tid = threadIdx.x;
  const int lane = tid & 63;
  const int wave = tid >> 6;
  const int hb = tid * 8;

  __shared__ float2 red[4];

  const float* tp = traj + (size_t)blk * H_N + hb;
  float4 t0 = *(const float4*)tp;
  float4 t1 = *(const float4*)(tp + 4);
  float2 c[8];
#pragma unroll
  for (int e = 0; e < 8; ++e) c[e] = ws2[hb + e];

  float hv[8] = {t0.x, t0.y, t0.z, t0.w, t1.x, t1.y, t1.z, t1.w};
  float p0 = 0.f, p1 = 0.f;
#pragma unroll
  for (int e = 0; e < 8; ++e) {
    const float rv = fast_tanh(hv[e]);
    p0 = fmaf(rv, c[e].x, p0);
    p1 = fmaf(rv, c[e].y, p1);
  }
  p0 = wave_sum63(p0);
  p1 = wave_sum63(p1);
  if (lane == 63) red[wave] = make_float2(p0, p1);
  __syncthreads();
  if (tid == 0) {
    float o0 = 0.f, o1 = 0.f;
#pragma unroll
    for (int w = 0; w < 4; ++w) {
      o0 += red[w].x;
      o1 += red[w].y;
    }
    ((float2*)out)[blk] = make_float2(o0, o1);
  }
}

// ----------------------- kernel1: the sequential RNN -----------------------
// 8 waves, EPT=4, barrier-FREE step sync: partials ring of 4 slots + LDS
// atomic counters. lane63 per wave: ds_write partial -> lgkmcnt(0) ->
// ds_add done_cnt[slot]. Consumers spin on an acquire-load (broadcast read),
// then run the baseline DPP stage-2. Ring depth 4 is race-free: writing
// slot(t) requires passing poll(t-1) => all waves wrote t-1 => all waves
// read t-2 (program order) => all waves read t-4.
__global__ __launch_bounds__(TPB) void rnn_fused(
    const float* __restrict__ input,   // (B,T,I)
    const float* __restrict__ noise,   // (B,T,H)
    const float* __restrict__ wi,      // (I,S,G)
    const float* __restrict__ unitwi,  // (I,S,1)
    const float* __restrict__ m_,      // (R,S,G)
    const float* __restrict__ n_,      // (R,S,G)
    const float* __restrict__ unitm,   // (R,S,1)
    const float* __restrict__ unitn,   // (R,S,1)
    const float* __restrict__ h0,      // (S,G)
    const float* __restrict__ unith0,  // (S,1)
    const float* __restrict__ bias,    // (S,1)
    const float* __restrict__ gb,      // (G,H)
    const float* __restrict__ uv,      // (1,H)
    const float* __restrict__ sup,     // (S,H)
    float* __restrict__ traj) {        // (B,T,H)
  const int tid = threadIdx.x;
  const int lane = tid & 63;
  const int wave = tid >> 6;
  const int b = blockIdx.x;
  const int hbase = tid * EPT;
  const int s = hbase >> 9;  // H/S = 512

  // Ring of 4 partial slots; [slot][0..7] live, [slot][8..15] stay zero
  // (lets stage-2 read lane&15 and row-reduce with zeros padding).
  __shared__ float2 parts[4][16];
  __shared__ unsigned done_cnt[4];
  __shared__ float4 xs4[T_N];  // x_t staged as float4 (w unused)

  // ---- setup: per-element proxy constants ----
  float cn0[EPT], cn1[EPT], cm0[EPT], cm1[EPT];
  float cw0[EPT], cw1[EPT], cw2[EPT];
  float cb[EPT], hh_[EPT];

  for (int e = 0; e < EPT; ++e) {
    const int hh = hbase + e;
    float gbh[G_N];
#pragma unroll
    for (int g = 0; g < G_N; ++g) gbh[g] = gb[g * H_N + hh];
    const float uvh = uv[hh];
    const float sv = sup[s * H_N + hh];

    auto comb = [&](const float* p, const float* up, int k) {
      float acc = up[k * S_N + s] * uvh;
#pragma unroll
      for (int g = 0; g < G_N; ++g)
        acc = fmaf(p[(k * S_N + s) * G_N + g], gbh[g], acc);
      return acc * sv;
    };

    cn0[e] = comb(n_, unitn, 0);
    cn1[e] = comb(n_, unitn, 1);
    cm0[e] = ALPHA_C * comb(m_, unitm, 0);
    cm1[e] = ALPHA_C * comb(m_, unitm, 1);
    cw0[e] = ALPHA_C * comb(wi, unitwi, 0);
    cw1[e] = ALPHA_C * comb(wi, unitwi, 1);
    cw2[e] = ALPHA_C * comb(wi, unitwi, 2);
    cb[e] = bias[s] * uvh * sv;
    hh_[e] = comb(h0, unith0, 0);
  }

  // packed layouts; dot in w-form: r = 1-2w, so
  // sum_e r_e*cn_e = (sum_e cn_e) + sum_e w_e*(-2 cn_e)
  v2f c2n[EPT];          // -2*(cn0,cn1) per element
  v2f cnsE, cnsD;        // sum of cn pairs over even/odd elements
  v2f cm0p[2], cm1p[2], cw0p[2], cw1p[2], cw2p[2], cbp[2];
  {
    v2f cnp[EPT];
#pragma unroll
    for (int e = 0; e < EPT; ++e) {
      cnp[e] = (v2f){cn0[e], cn1[e]};
      c2n[e] = -2.0f * cnp[e];
    }
    cnsE = cnp[0] + cnp[2];
    cnsD = cnp[1] + cnp[3];
  }
#pragma unroll
  for (int p2 = 0; p2 < 2; ++p2) {
    cm0p[p2] = (v2f){cm0[2 * p2], cm0[2 * p2 + 1]};
    cm1p[p2] = (v2f){cm1[2 * p2], cm1[2 * p2 + 1]};
    cw0p[p2] = (v2f){cw0[2 * p2], cw0[2 * p2 + 1]};
    cw1p[p2] = (v2f){cw1[2 * p2], cw1[2 * p2 + 1]};
    cw2p[p2] = (v2f){cw2[2 * p2], cw2[2 * p2 + 1]};
    cbp[p2] = (v2f){cb[2 * p2], cb[2 * p2 + 1]};
  }
  v2f h01 = (v2f){hh_[0], hh_[1]};
  v2f h23 = (v2f){hh_[2], hh_[3]};
  // initial w from h0
  v2f w01, w23;
  {
    float e0 = __builtin_amdgcn_exp2f(h01.x * TWO_LOG2E);
    float e1 = __builtin_amdgcn_exp2f(h01.y * TWO_LOG2E);
    float e2 = __builtin_amdgcn_exp2f(h23.x * TWO_LOG2E);
    float e3 = __builtin_amdgcn_exp2f(h23.y * TWO_LOG2E);
    w01 = (v2f){__builtin_amdgcn_rcpf(e0 + 1.0f),
                __builtin_amdgcn_rcpf(e1 + 1.0f)};
    w23 = (v2f){__builtin_amdgcn_rcpf(e2 + 1.0f),
                __builtin_amdgcn_rcpf(e3 + 1.0f)};
  }

  const float* zp = noise + ((size_t)b * T_N) * H_N + hbase;
  const float* xp = input + ((size_t)b * T_N) * I_N;
  float* tp = traj + ((size_t)b * T_N) * H_N + hbase;

  // stage x into LDS (thread t handles timestep t; TPB == T_N)
  {
    const float* xq = xp + tid * I_N;
    xs4[tid] = make_float4(xq[0], xq[1], xq[2], 0.0f);
  }
  // init counters + zero the 8 dead slots of all 4 ring buffers
  if (tid < 4) done_cnt[tid] = 0u;
  if (tid < 32) parts[tid >> 3][8 + (tid & 7)] = make_float2(0.f, 0.f);

  // depth-8 z prefetch ring (keeps 8 x 16B loads in flight per thread)
  float4 zr0 = *(const float4*)zp;
  float4 zr1 = *(const float4*)(zp + 1 * (size_t)H_N);
  float4 zr2 = *(const float4*)(zp + 2 * (size_t)H_N);
  float4 zr3 = *(const float4*)(zp + 3 * (size_t)H_N);
  float4 zr4 = *(const float4*)(zp + 4 * (size_t)H_N);
  float4 zr5 = *(const float4*)(zp + 5 * (size_t)H_N);
  float4 zr6 = *(const float4*)(zp + 6 * (size_t)H_N);
  float4 zr7 = *(const float4*)(zp + 7 * (size_t)H_N);

  __builtin_amdgcn_s_waitcnt(0xC07F);  // lgkmcnt(0)
  __builtin_amdgcn_s_barrier();        // one-time: staging + counter init
  __asm__ volatile("" ::: "memory");

  float4 xv = xs4[0];

  auto body = [&](int t, int slot, unsigned tgt, float4& zslot) {
    // prefetch z_{t+8} (HBM, ring depth 8) and x_{t+1} (LDS)
    const float4 z0 = zslot;
    const int tz = (t + 8 < T_N) ? t + 8 : T_N - 1;
    float4 zn = *(const float4*)(zp + (size_t)tz * H_N);
    const int tx = (t + 1 < T_N) ? t + 1 : T_N - 1;
    float4 xn = xs4[tx];

    // reduce-independent part of the update: bias + noise + x·wi
    v2f z01 = (v2f){z0.x, z0.y}, z23 = (v2f){z0.z, z0.w};
    v2f pre01 = cbp[0];
    pre01 += NSTD_C * z01;
    pre01 += xv.x * cw0p[0];
    pre01 += xv.y * cw1p[0];
    pre01 += xv.z * cw2p[0];
    v2f pre23 = cbp[1];
    pre23 += NSTD_C * z23;
    pre23 += xv.x * cw0p[1];
    pre23 += xv.y * cw1p[1];
    pre23 += xv.z * cw2p[1];

    // rank-2 dot partials in w-form (two independent chains)
    v2f accE = cnsE;
    accE += w01.x * c2n[0];
    accE += w23.x * c2n[2];
    v2f accD = cnsD;
    accD += w01.y * c2n[1];
    accD += w23.y * c2n[3];
    v2f accA = accE + accD;
    float pa0 = wave_sum63(accA.x);
    float pa1 = wave_sum63(accA.y);

    // producer: publish partial, then bump the slot counter (release)
    if (lane == 63) {
      parts[slot][wave] = make_float2(pa0, pa1);
      __asm__ volatile("" ::: "memory");
      __builtin_amdgcn_s_waitcnt(0xC07F);  // drain ds_write before the add
      __asm__ volatile("" ::: "memory");
      __hip_atomic_fetch_add(&done_cnt[slot], 1u, __ATOMIC_RELEASE,
                             __HIP_MEMORY_SCOPE_WORKGROUP);
    }

    // consumer: spin until all 8 waves published (broadcast read, uniform)
    while (__hip_atomic_load(&done_cnt[slot], __ATOMIC_ACQUIRE,
                             __HIP_MEMORY_SCOPE_WORKGROUP) < tgt) {
    }
    __asm__ volatile("" ::: "memory");

    // stage 2 (baseline): one b64 read + 3 row_shl DPP adds -> lane0 sums
    float2 v = parts[slot][lane & 15];
    DPP_ADD(v.x, 0x101, 0xf); DPP_ADD(v.x, 0x102, 0xf); DPP_ADD(v.x, 0x104, 0xf);
    DPP_ADD(v.y, 0x101, 0xf); DPP_ADD(v.y, 0x102, 0xf); DPP_ADD(v.y, 0x104, 0xf);
    const float a0 = rfl(v.x);
    const float a1 = rfl(v.y);

    // h <- 0.8h + pre + a0*cm0 + a1*cm1
    h01 = 0.8f * h01 + pre01;
    h01 += a0 * cm0p[0];
    h01 += a1 * cm1p[0];
    h23 = 0.8f * h23 + pre23;
    h23 += a0 * cm0p[1];
    h23 += a1 * cm1p[1];

    *(float4*)(tp + (size_t)t * H_N) = make_float4(h01.x, h01.y, h23.x, h23.y);

    // w = 1/(exp2(2log2e*h)+1); next step's dot consumes w directly
    float e0 = __builtin_amdgcn_exp2f(h01.x * TWO_LOG2E);
    float e1 = __builtin_amdgcn_exp2f(h01.y * TWO_LOG2E);
    float e2 = __builtin_amdgcn_exp2f(h23.x * TWO_LOG2E);
    float e3 = __builtin_amdgcn_exp2f(h23.y * TWO_LOG2E);
    w01 = (v2f){__builtin_amdgcn_rcpf(e0 + 1.0f),
                __builtin_amdgcn_rcpf(e1 + 1.0f)};
    w23 = (v2f){__builtin_amdgcn_rcpf(e2 + 1.0f),
                __builtin_amdgcn_rcpf(e3 + 1.0f)};

    zslot = zn;
    xv = xn;
  };

  for (int t = 0; t < T_N; t += 8) {
    const unsigned tg0 = (unsigned)(2 * t) + 8u;   // = 8*((t>>2)+1)
    const unsigned tg1 = tg0 + 8u;
    body(t,     0, tg0, zr0);
    body(t + 1, 1, tg0, zr1);
    body(t + 2, 2, tg0, zr2);
    body(t + 3, 3, tg0, zr3);
    body(t + 4, 0, tg1, zr4);
    body(t + 5, 1, tg1, zr5);
    body(t + 6, 2, tg1, zr6);
    body(t + 7, 3, tg1, zr7);
  }
}

extern "C" void kernel_launch(void* const* d_in, const int* in_sizes, int n_in,
                              void* d_out, int out_size, void* d_ws, size_t ws_size,
                              hipStream_t stream) {
  const float* input  = (const float*)d_in[0];
  const float* noise  = (const float*)d_in[1];
  const float* wi     = (const float*)d_in[2];
  const float* unitwi = (const float*)d_in[3];
  const float* m_     = (const float*)d_in[4];
  const float* n_     = (const float*)d_in[5];
  const float* unitm  = (const float*)d_in[6];
  const float* unitn  = (const float*)d_in[7];
  const float* wo     = (const float*)d_in[8];
  const float* h0     = (const float*)d_in[9];
  const float* unith0 = (const float*)d_in[10];
  const float* bias   = (const float*)d_in[11];
  const float* gb     = (const float*)d_in[12];
  const float* uv     = (const float*)d_in[13];
  const float* sup    = (const float*)d_in[14];

  float* out  = (float*)d_out;                  // (B,T,O) first
  float* traj = out + (size_t)B_N * T_N * O_N;  // then (B,T,H)
  float2* ws2 = (float2*)d_ws;                  // wo_full (H,2)

  wo_precomp<<<dim3(H_N / 256), dim3(256), 0, stream>>>(wo, gb, sup, ws2);
  rnn_fused<<<dim3(B_N), dim3(TPB), 0, stream>>>(
      input, noise, wi, unitwi, m_, n_, unitm, unitn, h0, unith0, bias,
      gb, uv, sup, traj);
  out_proj<<<dim3(B_N * T_N), dim3(256), 0, stream>>>(traj, ws2, out);
}

// Round 9
// 426.156 us; speedup vs baseline: 1.0705x; 1.0705x over previous
//
#include <hip/hip_runtime.h>

typedef float v2f __attribute__((ext_vector_type(2)));

// Problem constants (from reference)
constexpr int I_N = 3, H_N = 2048, O_N = 2, S_N = 4, G_N = 7;
constexpr int B_N = 32, T_N = 512;
constexpr int TPB = 512;          // threads per block (8 waves)
constexpr int EPT = H_N / TPB;    // 4 consecutive h-elements per thread
constexpr float ALPHA_C = 0.2f;
constexpr float NSTD_C = 0.05f;
constexpr float TWO_LOG2E = 2.885390081777927f;  // 2*log2(e)

// tanh(x) = 1 - 2/(exp2(2*log2e*x)+1); inf-safe both ends
__device__ __forceinline__ float fast_tanh(float x) {
  float e = __builtin_amdgcn_exp2f(x * TWO_LOG2E);
  return fmaf(-2.0f, __builtin_amdgcn_rcpf(e + 1.0f), 1.0f);
}

#define DPP_ADD(x, ctrl, rmask)                                                \
  x += __int_as_float(__builtin_amdgcn_update_dpp(                             \
      0, __float_as_int(x), (ctrl), (rmask), 0xf, true))

// Full 64-lane sum -> lane 63 (row_shr moves data to HIGHER lanes)
__device__ __forceinline__ float wave_sum63(float x) {
  DPP_ADD(x, 0x111, 0xf);  // row_shr:1
  DPP_ADD(x, 0x112, 0xf);  // row_shr:2
  DPP_ADD(x, 0x114, 0xf);  // row_shr:4
  DPP_ADD(x, 0x118, 0xf);  // row_shr:8
  DPP_ADD(x, 0x142, 0xa);  // row_bcast15 -> lane31
  DPP_ADD(x, 0x143, 0xc);  // row_bcast31 -> lane63
  return x;
}

__device__ __forceinline__ float rfl(float v) {
  return __int_as_float(__builtin_amdgcn_readfirstlane(__float_as_int(v)));
}

// ---------------- kernel0: precompute wo_full (H,2) into ws ----------------
__global__ __launch_bounds__(256) void wo_precomp(
    const float* __restrict__ wo, const float* __restrict__ gb,
    const float* __restrict__ sup, float2* __restrict__ ws2) {
  const int h = blockIdx.x * 256 + threadIdx.x;
  const int s = h >> 9;
  const float sv = sup[s * H_N + h];
  float c0 = 0.f, c1 = 0.f;
#pragma unroll
  for (int g = 0; g < G_N; ++g) {
    const float gv = gb[g * H_N + h];
    c0 = fmaf(wo[(0 * S_N + s) * G_N + g], gv, c0);
    c1 = fmaf(wo[(1 * S_N + s) * G_N + g], gv, c1);
  }
  ws2[h] = make_float2(c0 * sv, c1 * sv);
}

// ------------- kernel2: out[b,t] = tanh(traj[b,t,:]) @ wo_full -------------
__global__ __launch_bounds__(256) void out_proj(
    const float* __restrict__ traj, const float2* __restrict__ ws2,
    float* __restrict__ out) {
  const int blk = blockIdx.x;          // b*T + t
  const int tid = threadIdx.x;
  const int lane = tid & 63;
  const int wave = tid >> 6;
  const int hb = tid * 8;

  __shared__ float2 red[4];

  const float* tp = traj + (size_t)blk * H_N + hb;
  float4 t0 = *(const float4*)tp;
  float4 t1 = *(const float4*)(tp + 4);
  float2 c[8];
#pragma unroll
  for (int e = 0; e < 8; ++e) c[e] = ws2[hb + e];

  float hv[8] = {t0.x, t0.y, t0.z, t0.w, t1.x, t1.y, t1.z, t1.w};
  float p0 = 0.f, p1 = 0.f;
#pragma unroll
  for (int e = 0; e < 8; ++e) {
    const float rv = fast_tanh(hv[e]);
    p0 = fmaf(rv, c[e].x, p0);
    p1 = fmaf(rv, c[e].y, p1);
  }
  p0 = wave_sum63(p0);
  p1 = wave_sum63(p1);
  if (lane == 63) red[wave] = make_float2(p0, p1);
  __syncthreads();
  if (tid == 0) {
    float o0 = 0.f, o1 = 0.f;
#pragma unroll
    for (int w = 0; w < 4; ++w) {
      o0 += red[w].x;
      o1 += red[w].y;
    }
    ((float2*)out)[blk] = make_float2(o0, o1);
  }
}

// ----------------------- kernel1: the sequential RNN -----------------------
// Exact r0 skeleton (8 waves, EPT=4, depth-8 z-ring, b64+DPP+rfl stage-2,
// one s_barrier/step) + two chain cuts:
//  (1) hb = 0.8h + pre hoisted PRE-barrier (post-read update: 3 fma -> 2)
//  (2) w-form dot: w = 1/(e^{2h}+1), dot = cns + w*(-2cn) — drops the
//      r=1-2w fma from the tanh->dot chain.
__global__ __launch_bounds__(TPB) void rnn_fused(
    const float* __restrict__ input,   // (B,T,I)
    const float* __restrict__ noise,   // (B,T,H)
    const float* __restrict__ wi,      // (I,S,G)
    const float* __restrict__ unitwi,  // (I,S,1)
    const float* __restrict__ m_,      // (R,S,G)
    const float* __restrict__ n_,      // (R,S,G)
    const float* __restrict__ unitm,   // (R,S,1)
    const float* __restrict__ unitn,   // (R,S,1)
    const float* __restrict__ h0,      // (S,G)
    const float* __restrict__ unith0,  // (S,1)
    const float* __restrict__ bias,    // (S,1)
    const float* __restrict__ gb,      // (G,H)
    const float* __restrict__ uv,      // (1,H)
    const float* __restrict__ sup,     // (S,H)
    float* __restrict__ traj) {        // (B,T,H)
  const int tid = threadIdx.x;
  const int lane = tid & 63;
  const int wave = tid >> 6;
  const int b = blockIdx.x;
  const int hbase = tid * EPT;
  const int s = hbase >> 9;  // H/S = 512

  // Double-buffered wave partials: slots 0..7 live, 8..15 stay zero.
  __shared__ float2 parts[2][16];
  __shared__ float4 xs4[T_N];  // x_t staged as float4 (w unused)

  // ---- setup: per-element proxy constants ----
  float cn0[EPT], cn1[EPT], cm0[EPT], cm1[EPT];
  float cw0[EPT], cw1[EPT], cw2[EPT];
  float cb[EPT], hh_[EPT];

  for (int e = 0; e < EPT; ++e) {
    const int hh = hbase + e;
    float gbh[G_N];
#pragma unroll
    for (int g = 0; g < G_N; ++g) gbh[g] = gb[g * H_N + hh];
    const float uvh = uv[hh];
    const float sv = sup[s * H_N + hh];

    auto comb = [&](const float* p, const float* up, int k) {
      float acc = up[k * S_N + s] * uvh;
#pragma unroll
      for (int g = 0; g < G_N; ++g)
        acc = fmaf(p[(k * S_N + s) * G_N + g], gbh[g], acc);
      return acc * sv;
    };

    cn0[e] = comb(n_, unitn, 0);
    cn1[e] = comb(n_, unitn, 1);
    cm0[e] = ALPHA_C * comb(m_, unitm, 0);
    cm1[e] = ALPHA_C * comb(m_, unitm, 1);
    cw0[e] = ALPHA_C * comb(wi, unitwi, 0);
    cw1[e] = ALPHA_C * comb(wi, unitwi, 1);
    cw2[e] = ALPHA_C * comb(wi, unitwi, 2);
    cb[e] = bias[s] * uvh * sv;
    hh_[e] = comb(h0, unith0, 0);
  }

  // packed layouts; dot in w-form:
  // sum_e r_e*cn_e = (sum_e cn_e) + sum_e w_e*(-2 cn_e),  r = 1-2w
  v2f c2n[EPT];   // -2*(cn0,cn1) per element
  v2f cnsE, cnsD; // sums of cn pairs over even/odd elements
  v2f cm0p[2], cm1p[2], cw0p[2], cw1p[2], cw2p[2], cbp[2];
  {
    v2f cnp[EPT];
#pragma unroll
    for (int e = 0; e < EPT; ++e) {
      cnp[e] = (v2f){cn0[e], cn1[e]};
      c2n[e] = -2.0f * cnp[e];
    }
    cnsE = cnp[0] + cnp[2];
    cnsD = cnp[1] + cnp[3];
  }
#pragma unroll
  for (int p2 = 0; p2 < 2; ++p2) {
    cm0p[p2] = (v2f){cm0[2 * p2], cm0[2 * p2 + 1]};
    cm1p[p2] = (v2f){cm1[2 * p2], cm1[2 * p2 + 1]};
    cw0p[p2] = (v2f){cw0[2 * p2], cw0[2 * p2 + 1]};
    cw1p[p2] = (v2f){cw1[2 * p2], cw1[2 * p2 + 1]};
    cw2p[p2] = (v2f){cw2[2 * p2], cw2[2 * p2 + 1]};
    cbp[p2] = (v2f){cb[2 * p2], cb[2 * p2 + 1]};
  }
  v2f h01 = (v2f){hh_[0], hh_[1]};
  v2f h23 = (v2f){hh_[2], hh_[3]};
  // initial w from h0
  v2f w01, w23;
  {
    float e0 = __builtin_amdgcn_exp2f(h01.x * TWO_LOG2E);
    float e1 = __builtin_amdgcn_exp2f(h01.y * TWO_LOG2E);
    float e2 = __builtin_amdgcn_exp2f(h23.x * TWO_LOG2E);
    float e3 = __builtin_amdgcn_exp2f(h23.y * TWO_LOG2E);
    w01 = (v2f){__builtin_amdgcn_rcpf(e0 + 1.0f),
                __builtin_amdgcn_rcpf(e1 + 1.0f)};
    w23 = (v2f){__builtin_amdgcn_rcpf(e2 + 1.0f),
                __builtin_amdgcn_rcpf(e3 + 1.0f)};
  }

  const float* zp = noise + ((size_t)b * T_N) * H_N + hbase;
  const float* xp = input + ((size_t)b * T_N) * I_N;
  float* tp = traj + ((size_t)b * T_N) * H_N + hbase;

  // stage x into LDS (thread t handles timestep t; TPB == T_N)
  {
    const float* xq = xp + tid * I_N;
    xs4[tid] = make_float4(xq[0], xq[1], xq[2], 0.0f);
  }
  // zero the 8 dead slots of both partial buffers (once)
  if (tid < 16) parts[tid >> 3][8 + (tid & 7)] = make_float2(0.f, 0.f);

  // depth-8 z prefetch ring (keeps 8 x 16B loads in flight per thread)
  float4 zr0 = *(const float4*)zp;
  float4 zr1 = *(const float4*)(zp + 1 * (size_t)H_N);
  float4 zr2 = *(const float4*)(zp + 2 * (size_t)H_N);
  float4 zr3 = *(const float4*)(zp + 3 * (size_t)H_N);
  float4 zr4 = *(const float4*)(zp + 4 * (size_t)H_N);
  float4 zr5 = *(const float4*)(zp + 5 * (size_t)H_N);
  float4 zr6 = *(const float4*)(zp + 6 * (size_t)H_N);
  float4 zr7 = *(const float4*)(zp + 7 * (size_t)H_N);

  __builtin_amdgcn_s_waitcnt(0xC07F);  // lgkmcnt(0)
  __builtin_amdgcn_s_barrier();
  __asm__ volatile("" ::: "memory");

  float4 xv = xs4[0];

  auto body = [&](int t, int pb, float4& zslot) {
    // prefetch z_{t+8} (HBM, ring depth 8) and x_{t+1} (LDS)
    const float4 z0 = zslot;
    const int tz = (t + 8 < T_N) ? t + 8 : T_N - 1;
    float4 zn = *(const float4*)(zp + (size_t)tz * H_N);
    const int tx = (t + 1 < T_N) ? t + 1 : T_N - 1;
    float4 xn = xs4[tx];

    // reduce-independent part of the update: bias + noise + x·wi
    v2f z01 = (v2f){z0.x, z0.y}, z23 = (v2f){z0.z, z0.w};
    v2f pre01 = cbp[0];
    pre01 += NSTD_C * z01;
    pre01 += xv.x * cw0p[0];
    pre01 += xv.y * cw1p[0];
    pre01 += xv.z * cw2p[0];
    v2f pre23 = cbp[1];
    pre23 += NSTD_C * z23;
    pre23 += xv.x * cw0p[1];
    pre23 += xv.y * cw1p[1];
    pre23 += xv.z * cw2p[1];

    // hb-hoist: the a-independent part of the h-update, PRE-barrier
    v2f hb01 = 0.8f * h01 + pre01;
    v2f hb23 = 0.8f * h23 + pre23;

    // rank-2 dot partials in w-form (two independent chains)
    v2f accE = cnsE;
    accE += w01.x * c2n[0];
    accE += w23.x * c2n[2];
    v2f accD = cnsD;
    accD += w01.y * c2n[1];
    accD += w23.y * c2n[3];
    v2f accA = accE + accD;
    float pa0 = wave_sum63(accA.x);
    float pa1 = wave_sum63(accA.y);
    if (lane == 63) parts[pb][wave] = make_float2(pa0, pa1);

    __builtin_amdgcn_s_waitcnt(0xC07F);  // lgkmcnt(0) only
    __builtin_amdgcn_s_barrier();
    __asm__ volatile("" ::: "memory");

    // stage 2: one b64 read + 3 row_shl DPP adds -> lane0 = sum slots 0..7
    float2 v = parts[pb][lane & 15];
    DPP_ADD(v.x, 0x101, 0xf); DPP_ADD(v.x, 0x102, 0xf); DPP_ADD(v.x, 0x104, 0xf);
    DPP_ADD(v.y, 0x101, 0xf); DPP_ADD(v.y, 0x102, 0xf); DPP_ADD(v.y, 0x104, 0xf);
    const float a0 = rfl(v.x);
    const float a1 = rfl(v.y);

    // h <- hb + a0*cm0 + a1*cm1 (2 chained fma only)
    h01 = hb01 + a0 * cm0p[0];
    h01 += a1 * cm1p[0];
    h23 = hb23 + a0 * cm0p[1];
    h23 += a1 * cm1p[1];

    *(float4*)(tp + (size_t)t * H_N) = make_float4(h01.x, h01.y, h23.x, h23.y);

    // w = 1/(exp2(2log2e*h)+1); next step's dot consumes w directly
    float e0 = __builtin_amdgcn_exp2f(h01.x * TWO_LOG2E);
    float e1 = __builtin_amdgcn_exp2f(h01.y * TWO_LOG2E);
    float e2 = __builtin_amdgcn_exp2f(h23.x * TWO_LOG2E);
    float e3 = __builtin_amdgcn_exp2f(h23.y * TWO_LOG2E);
    w01 = (v2f){__builtin_amdgcn_rcpf(e0 + 1.0f),
                __builtin_amdgcn_rcpf(e1 + 1.0f)};
    w23 = (v2f){__builtin_amdgcn_rcpf(e2 + 1.0f),
                __builtin_amdgcn_rcpf(e3 + 1.0f)};

    zslot = zn;
    xv = xn;
  };

  for (int t = 0; t < T_N; t += 8) {
    body(t, 0, zr0);
    body(t + 1, 1, zr1);
    body(t + 2, 0, zr2);
    body(t + 3, 1, zr3);
    body(t + 4, 0, zr4);
    body(t + 5, 1, zr5);
    body(t + 6, 0, zr6);
    body(t + 7, 1, zr7);
  }
}

extern "C" void kernel_launch(void* const* d_in, const int* in_sizes, int n_in,
                              void* d_out, int out_size, void* d_ws, size_t ws_size,
                              hipStream_t stream) {
  const float* input  = (const float*)d_in[0];
  const float* noise  = (const float*)d_in[1];
  const float* wi     = (const float*)d_in[2];
  const float* unitwi = (const float*)d_in[3];
  const float* m_     = (const float*)d_in[4];
  const float* n_     = (const float*)d_in[5];
  const float* unitm  = (const float*)d_in[6];
  const float* unitn  = (const float*)d_in[7];
  const float* wo     = (const float*)d_in[8];
  const float* h0     = (const float*)d_in[9];
  const float* unith0 = (const float*)d_in[10];
  const float* bias   = (const float*)d_in[11];
  const float* gb     = (const float*)d_in[12];
  const float* uv     = (const float*)d_in[13];
  const float* sup    = (const float*)d_in[14];

  float* out  = (float*)d_out;                  // (B,T,O) first
  float* traj = out + (size_t)B_N * T_N * O_N;  // then (B,T,H)
  float2* ws2 = (float2*)d_ws;                  // wo_full (H,2)

  wo_precomp<<<dim3(H_N / 256), dim3(256), 0, stream>>>(wo, gb, sup, ws2);
  rnn_fused<<<dim3(B_N), dim3(TPB), 0, stream>>>(
      input, noise, wi, unitwi, m_, n_, unitm, unitn, h0, unith0, bias,
      gb, uv, sup, traj);
  out_proj<<<dim3(B_N * T_N), dim3(256), 0, stream>>>(traj, ws2, out);
}